// Round 10
// baseline (178.588 us; speedup 1.0000x reference)
//
#include <hip/hip_runtime.h>

#define NN 40000
#define DD 128
#define EE 640000
#define SLOPE 0.01f
#define CAP 64   // bucket capacity; Poisson(16) => overflow prob negligible

typedef __attribute__((ext_vector_type(8))) short  short8;   // 8 x bf16
typedef __attribute__((ext_vector_type(8))) unsigned short ushort8;
typedef __attribute__((ext_vector_type(4))) float  floatx4;  // MFMA acc

__device__ __forceinline__ float leaky1(float v) { return v >= 0.f ? v : v * SLOPE; }

__device__ __forceinline__ unsigned short f2bf(float f) {
    unsigned int u = __float_as_uint(f);
    u += 0x7fffu + ((u >> 16) & 1u);       // RNE
    return (unsigned short)(u >> 16);
}

// ---------------------------------------------------------------------------
// K0 k_init: cnt=0 + pack 4 weight mats into bf16 MFMA B-frag order
// ---------------------------------------------------------------------------
__global__ __launch_bounds__(256) void k_init(
    const float* __restrict__ Wh1, const float* __restrict__ Wf1,
    const float* __restrict__ Wg1, const float* __restrict__ Wg2,
    int* __restrict__ cnt, unsigned short* __restrict__ pk)
{
    const int gid = blockIdx.x * 256 + threadIdx.x;
    if (gid < NN) cnt[gid] = 0;

    if (gid < 8192) {
        const int mat = gid >> 11;
        const int rem = gid & 2047;
        const int ct  = rem >> 8;
        const int kc  = (rem >> 6) & 3;
        const int l   = rem & 63;
        const float* W = (mat == 0) ? Wh1 : (mat == 1) ? (Wf1 + 3 * DD)
                       : (mat == 2) ? Wg1 : Wg2;
        const int n  = ct * 16 + (l & 15);
        const int k0 = kc * 32 + (l >> 4) * 8;
        ushort8 v;
        #pragma unroll
        for (int j = 0; j < 8; ++j) v[j] = f2bf(W[(size_t)(k0 + j) * DD + n]);
        *(ushort8*)(pk + (size_t)gid * 8) = v;
    }
}

// ---------------------------------------------------------------------------
// K1 k_node_pre: DEFUSED from R9's pre_scatter (A/B test: fused kernel ran
// 47us vs parts 26+11 measured standalone -> fusion suspected net-negative;
// R7's +3.4 attribution was confounded with a gather revert).
// ---------------------------------------------------------------------------
__global__ __launch_bounds__(512) void k_node_pre(
    const float* __restrict__ x,
    const unsigned short* __restrict__ pk,
    const float* __restrict__ pos, const float* __restrict__ Wf1,
    const float* __restrict__ bh1, const float* __restrict__ Wh2,
    const float* __restrict__ bh2, const float* __restrict__ bf1,
    unsigned short* __restrict__ ub, float* __restrict__ delta)
{
    __shared__ unsigned short xt[64 * 136];   // bf16 x tile
    __shared__ unsigned short ul[64 * 136];   // bf16 u tile
    const int t  = threadIdx.x;               // 0..511
    const int w  = t >> 6, l = t & 63;        // w 0..7
    const int lm = l & 15, q = l >> 4;
    const int rowb = blockIdx.x * 64;

    // ---- stage x -> bf16 LDS ----
    {
        const int row = t >> 3;               // 0..63
        const int c0  = (t & 7) * 16;         // 0,16,...,112
        const float* xp = x + (size_t)(rowb + row) * DD + c0;
        #pragma unroll
        for (int p = 0; p < 2; ++p) {
            const float4 v0 = *(const float4*)(xp + p * 8);
            const float4 v1 = *(const float4*)(xp + p * 8 + 4);
            ushort8 o;
            o[0] = f2bf(v0.x); o[1] = f2bf(v0.y); o[2] = f2bf(v0.z); o[3] = f2bf(v0.w);
            o[4] = f2bf(v1.x); o[5] = f2bf(v1.y); o[6] = f2bf(v1.z); o[7] = f2bf(v1.w);
            *(ushort8*)(xt + row * 136 + c0 + p * 8) = o;
        }
    }
    __syncthreads();

    const bool upath = w < 4;
    const int wl   = upath ? w : w - 4;
    const int row0 = wl * 16;
    const unsigned short* pkm = upath ? (pk + 16384) : pk;   // Wf1[3:] / Wh1

    floatx4 acc[8];
    #pragma unroll
    for (int ct = 0; ct < 8; ++ct) acc[ct] = 0.f;

    #pragma unroll
    for (int kc = 0; kc < 4; ++kc) {
        const short8 a = *(const short8*)(xt + (row0 + lm) * 136 + kc * 32 + q * 8);
        #pragma unroll
        for (int ct = 0; ct < 8; ++ct) {
            const short8 b = *(const short8*)(pkm + (size_t)((ct * 4 + kc) * 64 + l) * 8);
            acc[ct] = __builtin_amdgcn_mfma_f32_16x16x32_bf16(a, b, acc[ct], 0, 0, 0);
        }
    }

    // D layout: row=q*4+r, col=ct*16+lm (m89/m91-verified)
    if (upath) {
        float px[4][3];
        #pragma unroll
        for (int r = 0; r < 4; ++r) {
            const int rr = rowb + row0 + q * 4 + r;
            px[r][0] = pos[rr * 3 + 0];
            px[r][1] = pos[rr * 3 + 1];
            px[r][2] = pos[rr * 3 + 2];
        }
        #pragma unroll
        for (int ct = 0; ct < 8; ++ct) {
            const int col = ct * 16 + lm;
            const float bfv = bf1[col];
            const float w0 = Wf1[0 * DD + col];
            const float w1 = Wf1[1 * DD + col];
            const float w2 = Wf1[2 * DD + col];
            #pragma unroll
            for (int r = 0; r < 4; ++r) {
                const float uv = acc[ct][r] + bfv
                               + px[r][0] * w0 + px[r][1] * w1 + px[r][2] * w2;
                ul[(row0 + q * 4 + r) * 136 + col] = f2bf(uv);
            }
        }
    } else {
        float p[4][3] = {};
        #pragma unroll
        for (int ct = 0; ct < 8; ++ct) {
            const int col = ct * 16 + lm;
            const float b1 = bh1[col];
            const float wh20 = Wh2[col * 3 + 0];
            const float wh21 = Wh2[col * 3 + 1];
            const float wh22 = Wh2[col * 3 + 2];
            #pragma unroll
            for (int r = 0; r < 4; ++r) {
                const float hv = leaky1(acc[ct][r] + b1);
                p[r][0] += hv * wh20;
                p[r][1] += hv * wh21;
                p[r][2] += hv * wh22;
            }
        }
        #pragma unroll
        for (int m = 1; m < 16; m <<= 1) {
            #pragma unroll
            for (int r = 0; r < 4; ++r) {
                #pragma unroll
                for (int k = 0; k < 3; ++k)
                    p[r][k] += __shfl_xor(p[r][k], m);
            }
        }
        if (lm < 12) {
            const int r = lm / 3, k = lm - 3 * (lm / 3);
            delta[(size_t)(rowb + row0 + q * 4 + r) * 3 + k] = tanhf(p[r][k] + bh2[k]);
        }
    }
    __syncthreads();

    // coalesced u store: 1024 x 16B chunks over 512 threads (2 each)
    #pragma unroll
    for (int k = 0; k < 2; ++k) {
        const int idx = t + k * 512;
        const int row = idx >> 4;
        const int c8  = (idx & 15) * 8;
        *(ushort8*)(ub + (size_t)(rowb + row) * DD + c8) =
            *(const ushort8*)(ul + row * 136 + c8);
    }
}

// ---------------------------------------------------------------------------
// K2 k_scatter: standalone, R9 int2-MLP geometry repackaged as 4096 x 256-thr
// blocks (8 blocks/CU residency vs 4 at 512thr). Same 131072 threads/group,
// 2 consecutive edges per iter, stride 262144; g=bid&7 XCD-aligned.
// ---------------------------------------------------------------------------
__global__ __launch_bounds__(256) void k_scatter(const int* __restrict__ ei,
                                                 int* __restrict__ cnt,
                                                 unsigned short* __restrict__ esrc)
{
    const int bid = blockIdx.x;
    const int g   = bid & 7;
    const int lb  = bid >> 3;                 // 0..511
    const int dlo = g * 5000;
    const int dhi = dlo + 5000;

    for (int e = (lb * 256 + threadIdx.x) * 2; e < EE; e += 262144) {
        const int2 dp = *(const int2*)(ei + EE + e);
        const int2 sp = *(const int2*)(ei + e);
        if (dp.x >= dlo && dp.x < dhi) {
            const int p = atomicAdd(&cnt[dp.x], 1);
            if (p < CAP) esrc[(size_t)dp.x * CAP + p] = (unsigned short)sp.x;
        }
        if (dp.y >= dlo && dp.y < dhi) {
            const int p = atomicAdd(&cnt[dp.y], 1);
            if (p < CAP) esrc[(size_t)dp.y * CAP + p] = (unsigned short)sp.y;
        }
    }
}

// ---------------------------------------------------------------------------
// K3 k_gather (R2/R7 predicated form — at its VALU roofline, do not touch)
// ---------------------------------------------------------------------------
__global__ __launch_bounds__(256) void k_gather(
    const int* __restrict__ cnt, const unsigned short* __restrict__ esrc,
    const float* __restrict__ pos, const float* __restrict__ delta,
    const float* __restrict__ Wf1, const unsigned short* __restrict__ ub,
    unsigned short* __restrict__ aggrb)
{
    const int t    = threadIdx.x;
    const int lane = t & 63;
    const int n    = blockIdx.x * 4 + (t >> 6);
    const int grp  = lane >> 4;          // 0..3: handles edge j + 4k + grp
    const int li   = lane & 15;
    const int c    = li * 8;             // this lane's 8 cols

    const float q0 = delta[n * 3 + 0] - pos[n * 3 + 0];
    const float q1 = delta[n * 3 + 1] - pos[n * 3 + 1];
    const float q2 = delta[n * 3 + 2] - pos[n * 3 + 2];

    // v[8] = q . Wf1[0:3, c..c+7]   (bf1 already folded into ub by node_pre)
    float v[8];
    #pragma unroll
    for (int h = 0; h < 2; ++h) {
        const float4 w0 = *(const float4*)(Wf1 + 0 * DD + c + h * 4);
        const float4 w1 = *(const float4*)(Wf1 + 1 * DD + c + h * 4);
        const float4 w2 = *(const float4*)(Wf1 + 2 * DD + c + h * 4);
        v[h * 4 + 0] = q0 * w0.x + q1 * w1.x + q2 * w2.x;
        v[h * 4 + 1] = q0 * w0.y + q1 * w1.y + q2 * w2.y;
        v[h * 4 + 2] = q0 * w0.z + q1 * w1.z + q2 * w2.z;
        v[h * 4 + 3] = q0 * w0.w + q1 * w1.w + q2 * w2.w;
    }

    const int s_all = (int)esrc[(size_t)n * CAP + lane];   // 64 bucket slots
    const int d = min(cnt[n], CAP);

    float a[8] = {0.f, 0.f, 0.f, 0.f, 0.f, 0.f, 0.f, 0.f};

    for (int j = 0; j < d; j += 16) {
        uint4 u[4];
        bool vld[4];
        #pragma unroll
        for (int k = 0; k < 4; ++k) {
            const int e = j + 4 * k + grp;
            vld[k] = e < d;
            int src = __shfl(s_all, e & 63);
            src = vld[k] ? src : 0;
            u[k] = *(const uint4*)(ub + (size_t)src * DD + c);
        }
        #pragma unroll
        for (int k = 0; k < 4; ++k) {
            if (vld[k]) {
                const unsigned int uu0 = u[k].x, uu1 = u[k].y, uu2 = u[k].z, uu3 = u[k].w;
                const float e0 = __uint_as_float(uu0 << 16)         + v[0];
                const float e1 = __uint_as_float(uu0 & 0xffff0000u) + v[1];
                const float e2 = __uint_as_float(uu1 << 16)         + v[2];
                const float e3 = __uint_as_float(uu1 & 0xffff0000u) + v[3];
                const float e4 = __uint_as_float(uu2 << 16)         + v[4];
                const float e5 = __uint_as_float(uu2 & 0xffff0000u) + v[5];
                const float e6 = __uint_as_float(uu3 << 16)         + v[6];
                const float e7 = __uint_as_float(uu3 & 0xffff0000u) + v[7];
                a[0] += fmaxf(e0, e0 * SLOPE);
                a[1] += fmaxf(e1, e1 * SLOPE);
                a[2] += fmaxf(e2, e2 * SLOPE);
                a[3] += fmaxf(e3, e3 * SLOPE);
                a[4] += fmaxf(e4, e4 * SLOPE);
                a[5] += fmaxf(e5, e5 * SLOPE);
                a[6] += fmaxf(e6, e6 * SLOPE);
                a[7] += fmaxf(e7, e7 * SLOPE);
            }
        }
    }

    // combine the 4 edge groups
    #pragma unroll
    for (int i = 0; i < 8; ++i) {
        a[i] += __shfl_xor(a[i], 16);
        a[i] += __shfl_xor(a[i], 32);
    }

    if (grp == 0) {
        uint4 st;
        st.x = ((unsigned int)f2bf(a[1]) << 16) | (unsigned int)f2bf(a[0]);
        st.y = ((unsigned int)f2bf(a[3]) << 16) | (unsigned int)f2bf(a[2]);
        st.z = ((unsigned int)f2bf(a[5]) << 16) | (unsigned int)f2bf(a[4]);
        st.w = ((unsigned int)f2bf(a[7]) << 16) | (unsigned int)f2bf(a[6]);
        *(uint4*)(aggrb + (size_t)n * DD + c) = st;
    }
}

// ---------------------------------------------------------------------------
// K4 k_node_out (unchanged)
// ---------------------------------------------------------------------------
__global__ __launch_bounds__(256) void k_node_out(
    const unsigned short* __restrict__ aggrb, const unsigned short* __restrict__ pk,
    const float* __restrict__ x,
    const float* __restrict__ bg1, const float* __restrict__ bg2,
    float* __restrict__ out)
{
    __shared__ unsigned short gl[64 * 136];
    __shared__ float          ol[64 * 132];
    const int t  = threadIdx.x;
    const int w  = t >> 6, l = t & 63;
    const int lm = l & 15, q = l >> 4;
    const int rowb = blockIdx.x * 64;
    const int row0 = rowb + w * 16;

    const unsigned short* pkg1 = pk + 32768;
    const unsigned short* pkg2 = pk + 49152;

    floatx4 gacc[8];
    #pragma unroll
    for (int ct = 0; ct < 8; ++ct) gacc[ct] = 0.f;

    #pragma unroll
    for (int kc = 0; kc < 4; ++kc) {
        const short8 a = *(const short8*)(aggrb + (size_t)(row0 + lm) * DD + kc * 32 + q * 8);
        #pragma unroll
        for (int ct = 0; ct < 8; ++ct) {
            const short8 b = *(const short8*)(pkg1 + (size_t)((ct * 4 + kc) * 64 + l) * 8);
            gacc[ct] = __builtin_amdgcn_mfma_f32_16x16x32_bf16(a, b, gacc[ct], 0, 0, 0);
        }
    }

    #pragma unroll
    for (int ct = 0; ct < 8; ++ct) {
        const int col = ct * 16 + lm;
        const float b1 = bg1[col];
        #pragma unroll
        for (int r = 0; r < 4; ++r)
            gl[(w * 16 + q * 4 + r) * 136 + col] = f2bf(leaky1(gacc[ct][r] + b1));
    }
    __syncthreads();

    floatx4 oacc[8];
    #pragma unroll
    for (int ct = 0; ct < 8; ++ct) oacc[ct] = 0.f;

    #pragma unroll
    for (int kc = 0; kc < 4; ++kc) {
        const short8 a = *(const short8*)(gl + (size_t)(w * 16 + lm) * 136 + kc * 32 + q * 8);
        #pragma unroll
        for (int ct = 0; ct < 8; ++ct) {
            const short8 b = *(const short8*)(pkg2 + (size_t)((ct * 4 + kc) * 64 + l) * 8);
            oacc[ct] = __builtin_amdgcn_mfma_f32_16x16x32_bf16(a, b, oacc[ct], 0, 0, 0);
        }
    }

    __syncthreads();
    #pragma unroll
    for (int ct = 0; ct < 8; ++ct) {
        const int col = ct * 16 + lm;
        #pragma unroll
        for (int r = 0; r < 4; ++r)
            ol[(w * 16 + q * 4 + r) * 132 + col] = oacc[ct][r];
    }
    __syncthreads();

    #pragma unroll
    for (int k = 0; k < 8; ++k) {
        const int idx = t + k * 256;
        const int row = idx >> 5;
        const int c4  = (idx & 31) * 4;
        const float4 ov = *(const float4*)(ol + row * 132 + c4);
        const float4 bv = *(const float4*)(bg2 + c4);
        const size_t o  = (size_t)(rowb + row) * DD + c4;
        const float4 xv = *(const float4*)(x + o);
        float4 rv;
        rv.x = xv.x + ov.x + bv.x;
        rv.y = xv.y + ov.y + bv.y;
        rv.z = xv.z + ov.z + bv.z;
        rv.w = xv.w + ov.w + bv.w;
        *(float4*)(out + o) = rv;
    }
}

// ---------------------------------------------------------------------------
extern "C" void kernel_launch(void* const* d_in, const int* in_sizes, int n_in,
                              void* d_out, int out_size, void* d_ws, size_t ws_size,
                              hipStream_t stream)
{
    const float* x   = (const float*)d_in[0];
    const float* pos = (const float*)d_in[1];
    const int*   ei  = (const int*)d_in[2];
    const float* Wh1 = (const float*)d_in[3];
    const float* bh1 = (const float*)d_in[4];
    const float* Wh2 = (const float*)d_in[5];
    const float* bh2 = (const float*)d_in[6];
    const float* Wf1 = (const float*)d_in[7];
    const float* bf1 = (const float*)d_in[8];
    const float* Wg1 = (const float*)d_in[9];
    const float* bg1 = (const float*)d_in[10];
    const float* Wg2 = (const float*)d_in[11];
    const float* bg2 = (const float*)d_in[12];
    float* out = (float*)d_out;

    unsigned short* ub    = (unsigned short*)d_ws;          // NN*DD bf16
    unsigned short* aggrb = ub + (size_t)NN * DD;           // NN*DD bf16
    unsigned short* pk    = aggrb + (size_t)NN * DD;        // 4*16384 bf16
    float* delta = (float*)(pk + 65536);                    // NN*3
    int*   cnt   = (int*)(delta + (size_t)NN * 3);          // NN
    unsigned short* esrc = (unsigned short*)(cnt + NN);     // NN*CAP ushort

    k_init<<<160, 256, 0, stream>>>(Wh1, Wf1, Wg1, Wg2, cnt, pk);
    k_node_pre<<<625, 512, 0, stream>>>(x, pk, pos, Wf1, bh1, Wh2, bh2, bf1,
                                        ub, delta);
    k_scatter<<<4096, 256, 0, stream>>>(ei, cnt, esrc);
    k_gather<<<NN / 4, 256, 0, stream>>>(cnt, esrc, pos, delta, Wf1, ub, aggrb);
    k_node_out<<<NN / 64, 256, 0, stream>>>(aggrb, pk, x, bg1, bg2, out);
}

// Round 11
// 166.804 us; speedup vs baseline: 1.0706x; 1.0706x over previous
//
#include <hip/hip_runtime.h>

#define NN 40000
#define DD 128
#define EE 640000
#define SLOPE 0.01f
#define CAP 64   // bucket capacity; Poisson(16) => overflow prob negligible

typedef __attribute__((ext_vector_type(8))) short  short8;   // 8 x bf16
typedef __attribute__((ext_vector_type(8))) unsigned short ushort8;
typedef __attribute__((ext_vector_type(4))) float  floatx4;  // MFMA acc

__device__ __forceinline__ float leaky1(float v) { return v >= 0.f ? v : v * SLOPE; }

__device__ __forceinline__ unsigned short f2bf(float f) {
    unsigned int u = __float_as_uint(f);
    u += 0x7fffu + ((u >> 16) & 1u);       // RNE
    return (unsigned short)(u >> 16);
}

// ---------------------------------------------------------------------------
// K0 k_init: cnt=0 + pack 4 weight mats into bf16 MFMA B-frag order
// ---------------------------------------------------------------------------
__global__ __launch_bounds__(256) void k_init(
    const float* __restrict__ Wh1, const float* __restrict__ Wf1,
    const float* __restrict__ Wg1, const float* __restrict__ Wg2,
    int* __restrict__ cnt, unsigned short* __restrict__ pk)
{
    const int gid = blockIdx.x * 256 + threadIdx.x;
    if (gid < NN) cnt[gid] = 0;

    if (gid < 8192) {
        const int mat = gid >> 11;
        const int rem = gid & 2047;
        const int ct  = rem >> 8;
        const int kc  = (rem >> 6) & 3;
        const int l   = rem & 63;
        const float* W = (mat == 0) ? Wh1 : (mat == 1) ? (Wf1 + 3 * DD)
                       : (mat == 2) ? Wg1 : Wg2;
        const int n  = ct * 16 + (l & 15);
        const int k0 = kc * 32 + (l >> 4) * 8;
        ushort8 v;
        #pragma unroll
        for (int j = 0; j < 8; ++j) v[j] = f2bf(W[(size_t)(k0 + j) * DD + n]);
        *(ushort8*)(pk + (size_t)gid * 8) = v;
    }
}

// ---------------------------------------------------------------------------
// K1 k_pre_scatter: FUSED node_pre + scatter (R9/R10 A/B: fusion is worth
// ~6us via launch-gap elimination). NEW this round: PRE BLOCKS FIRST
// (bids 0..624), scatter bids 625..2672. Rationale: 512-thr blocks -> 1024
// resident blocks max; with scatter's 2048 blocks first, pre serialized
// behind a full occupancy wave (fused = 47us ~ scatter + pre tail). Pre
// first => first wave = all 625 pre + ~400 scatter: MFMA overlaps atomic
// latency. Scatter geometry identical: g=bid&7 (bids 625..2672 cover each
// residue exactly 256x), lb=(bid-625)>>3, int2 2-edge loads, stride 262144.
// ---------------------------------------------------------------------------
__global__ __launch_bounds__(512) void k_pre_scatter(
    const float* __restrict__ x,
    const unsigned short* __restrict__ pk,
    const float* __restrict__ pos, const float* __restrict__ Wf1,
    const float* __restrict__ bh1, const float* __restrict__ Wh2,
    const float* __restrict__ bh2, const float* __restrict__ bf1,
    const int* __restrict__ ei,
    unsigned short* __restrict__ ub, float* __restrict__ delta,
    int* __restrict__ cnt, unsigned short* __restrict__ esrc)
{
    __shared__ unsigned short xt[64 * 136];   // bf16 x tile (pre path only)
    __shared__ unsigned short ul[64 * 136];   // bf16 u tile (pre path only)
    const int bid = blockIdx.x;
    const int t   = threadIdx.x;              // 0..511

    if (bid >= 625) {
        // ---------------- scatter path ----------------
        const int g   = bid & 7;
        const int lb  = (bid - 625) >> 3;     // 0..255
        const int dlo = g * 5000;
        const int dhi = dlo + 5000;

        for (int e = (lb * 512 + t) * 2; e < EE; e += 262144) {
            const int2 dp = *(const int2*)(ei + EE + e);
            const int2 sp = *(const int2*)(ei + e);
            if (dp.x >= dlo && dp.x < dhi) {
                const int p = atomicAdd(&cnt[dp.x], 1);
                if (p < CAP) esrc[(size_t)dp.x * CAP + p] = (unsigned short)sp.x;
            }
            if (dp.y >= dlo && dp.y < dhi) {
                const int p = atomicAdd(&cnt[dp.y], 1);
                if (p < CAP) esrc[(size_t)dp.y * CAP + p] = (unsigned short)sp.y;
            }
        }
        return;
    }

    // ---------------- node_pre path ----------------
    const int w  = t >> 6, l = t & 63;        // w 0..7
    const int lm = l & 15, q = l >> 4;
    const int rowb = bid * 64;

    // ---- stage x -> bf16 LDS ----
    {
        const int row = t >> 3;               // 0..63
        const int c0  = (t & 7) * 16;         // 0,16,...,112
        const float* xp = x + (size_t)(rowb + row) * DD + c0;
        #pragma unroll
        for (int p = 0; p < 2; ++p) {
            const float4 v0 = *(const float4*)(xp + p * 8);
            const float4 v1 = *(const float4*)(xp + p * 8 + 4);
            ushort8 o;
            o[0] = f2bf(v0.x); o[1] = f2bf(v0.y); o[2] = f2bf(v0.z); o[3] = f2bf(v0.w);
            o[4] = f2bf(v1.x); o[5] = f2bf(v1.y); o[6] = f2bf(v1.z); o[7] = f2bf(v1.w);
            *(ushort8*)(xt + row * 136 + c0 + p * 8) = o;
        }
    }
    __syncthreads();

    const bool upath = w < 4;
    const int wl   = upath ? w : w - 4;
    const int row0 = wl * 16;
    const unsigned short* pkm = upath ? (pk + 16384) : pk;   // Wf1[3:] / Wh1

    floatx4 acc[8];
    #pragma unroll
    for (int ct = 0; ct < 8; ++ct) acc[ct] = 0.f;

    #pragma unroll
    for (int kc = 0; kc < 4; ++kc) {
        const short8 a = *(const short8*)(xt + (row0 + lm) * 136 + kc * 32 + q * 8);
        #pragma unroll
        for (int ct = 0; ct < 8; ++ct) {
            const short8 b = *(const short8*)(pkm + (size_t)((ct * 4 + kc) * 64 + l) * 8);
            acc[ct] = __builtin_amdgcn_mfma_f32_16x16x32_bf16(a, b, acc[ct], 0, 0, 0);
        }
    }

    // D layout: row=q*4+r, col=ct*16+lm (m89/m91-verified)
    if (upath) {
        float px[4][3];
        #pragma unroll
        for (int r = 0; r < 4; ++r) {
            const int rr = rowb + row0 + q * 4 + r;
            px[r][0] = pos[rr * 3 + 0];
            px[r][1] = pos[rr * 3 + 1];
            px[r][2] = pos[rr * 3 + 2];
        }
        #pragma unroll
        for (int ct = 0; ct < 8; ++ct) {
            const int col = ct * 16 + lm;
            const float bfv = bf1[col];
            const float w0 = Wf1[0 * DD + col];
            const float w1 = Wf1[1 * DD + col];
            const float w2 = Wf1[2 * DD + col];
            #pragma unroll
            for (int r = 0; r < 4; ++r) {
                const float uv = acc[ct][r] + bfv
                               + px[r][0] * w0 + px[r][1] * w1 + px[r][2] * w2;
                ul[(row0 + q * 4 + r) * 136 + col] = f2bf(uv);
            }
        }
    } else {
        float p[4][3] = {};
        #pragma unroll
        for (int ct = 0; ct < 8; ++ct) {
            const int col = ct * 16 + lm;
            const float b1 = bh1[col];
            const float wh20 = Wh2[col * 3 + 0];
            const float wh21 = Wh2[col * 3 + 1];
            const float wh22 = Wh2[col * 3 + 2];
            #pragma unroll
            for (int r = 0; r < 4; ++r) {
                const float hv = leaky1(acc[ct][r] + b1);
                p[r][0] += hv * wh20;
                p[r][1] += hv * wh21;
                p[r][2] += hv * wh22;
            }
        }
        #pragma unroll
        for (int m = 1; m < 16; m <<= 1) {
            #pragma unroll
            for (int r = 0; r < 4; ++r) {
                #pragma unroll
                for (int k = 0; k < 3; ++k)
                    p[r][k] += __shfl_xor(p[r][k], m);
            }
        }
        if (lm < 12) {
            const int r = lm / 3, k = lm - 3 * (lm / 3);
            delta[(size_t)(rowb + row0 + q * 4 + r) * 3 + k] = tanhf(p[r][k] + bh2[k]);
        }
    }
    __syncthreads();

    // coalesced u store: 1024 x 16B chunks over 512 threads (2 each)
    #pragma unroll
    for (int k = 0; k < 2; ++k) {
        const int idx = t + k * 512;
        const int row = idx >> 4;
        const int c8  = (idx & 15) * 8;
        *(ushort8*)(ub + (size_t)(rowb + row) * DD + c8) =
            *(const ushort8*)(ul + row * 136 + c8);
    }
}

// ---------------------------------------------------------------------------
// K3 k_gather (R2/R7 predicated form — at its VALU roofline, do not touch)
// ---------------------------------------------------------------------------
__global__ __launch_bounds__(256) void k_gather(
    const int* __restrict__ cnt, const unsigned short* __restrict__ esrc,
    const float* __restrict__ pos, const float* __restrict__ delta,
    const float* __restrict__ Wf1, const unsigned short* __restrict__ ub,
    unsigned short* __restrict__ aggrb)
{
    const int t    = threadIdx.x;
    const int lane = t & 63;
    const int n    = blockIdx.x * 4 + (t >> 6);
    const int grp  = lane >> 4;          // 0..3: handles edge j + 4k + grp
    const int li   = lane & 15;
    const int c    = li * 8;             // this lane's 8 cols

    const float q0 = delta[n * 3 + 0] - pos[n * 3 + 0];
    const float q1 = delta[n * 3 + 1] - pos[n * 3 + 1];
    const float q2 = delta[n * 3 + 2] - pos[n * 3 + 2];

    // v[8] = q . Wf1[0:3, c..c+7]   (bf1 already folded into ub by node_pre)
    float v[8];
    #pragma unroll
    for (int h = 0; h < 2; ++h) {
        const float4 w0 = *(const float4*)(Wf1 + 0 * DD + c + h * 4);
        const float4 w1 = *(const float4*)(Wf1 + 1 * DD + c + h * 4);
        const float4 w2 = *(const float4*)(Wf1 + 2 * DD + c + h * 4);
        v[h * 4 + 0] = q0 * w0.x + q1 * w1.x + q2 * w2.x;
        v[h * 4 + 1] = q0 * w0.y + q1 * w1.y + q2 * w2.y;
        v[h * 4 + 2] = q0 * w0.z + q1 * w1.z + q2 * w2.z;
        v[h * 4 + 3] = q0 * w0.w + q1 * w1.w + q2 * w2.w;
    }

    const int s_all = (int)esrc[(size_t)n * CAP + lane];   // 64 bucket slots
    const int d = min(cnt[n], CAP);

    float a[8] = {0.f, 0.f, 0.f, 0.f, 0.f, 0.f, 0.f, 0.f};

    for (int j = 0; j < d; j += 16) {
        uint4 u[4];
        bool vld[4];
        #pragma unroll
        for (int k = 0; k < 4; ++k) {
            const int e = j + 4 * k + grp;
            vld[k] = e < d;
            int src = __shfl(s_all, e & 63);
            src = vld[k] ? src : 0;
            u[k] = *(const uint4*)(ub + (size_t)src * DD + c);
        }
        #pragma unroll
        for (int k = 0; k < 4; ++k) {
            if (vld[k]) {
                const unsigned int uu0 = u[k].x, uu1 = u[k].y, uu2 = u[k].z, uu3 = u[k].w;
                const float e0 = __uint_as_float(uu0 << 16)         + v[0];
                const float e1 = __uint_as_float(uu0 & 0xffff0000u) + v[1];
                const float e2 = __uint_as_float(uu1 << 16)         + v[2];
                const float e3 = __uint_as_float(uu1 & 0xffff0000u) + v[3];
                const float e4 = __uint_as_float(uu2 << 16)         + v[4];
                const float e5 = __uint_as_float(uu2 & 0xffff0000u) + v[5];
                const float e6 = __uint_as_float(uu3 << 16)         + v[6];
                const float e7 = __uint_as_float(uu3 & 0xffff0000u) + v[7];
                a[0] += fmaxf(e0, e0 * SLOPE);
                a[1] += fmaxf(e1, e1 * SLOPE);
                a[2] += fmaxf(e2, e2 * SLOPE);
                a[3] += fmaxf(e3, e3 * SLOPE);
                a[4] += fmaxf(e4, e4 * SLOPE);
                a[5] += fmaxf(e5, e5 * SLOPE);
                a[6] += fmaxf(e6, e6 * SLOPE);
                a[7] += fmaxf(e7, e7 * SLOPE);
            }
        }
    }

    // combine the 4 edge groups
    #pragma unroll
    for (int i = 0; i < 8; ++i) {
        a[i] += __shfl_xor(a[i], 16);
        a[i] += __shfl_xor(a[i], 32);
    }

    if (grp == 0) {
        uint4 st;
        st.x = ((unsigned int)f2bf(a[1]) << 16) | (unsigned int)f2bf(a[0]);
        st.y = ((unsigned int)f2bf(a[3]) << 16) | (unsigned int)f2bf(a[2]);
        st.z = ((unsigned int)f2bf(a[5]) << 16) | (unsigned int)f2bf(a[4]);
        st.w = ((unsigned int)f2bf(a[7]) << 16) | (unsigned int)f2bf(a[6]);
        *(uint4*)(aggrb + (size_t)n * DD + c) = st;
    }
}

// ---------------------------------------------------------------------------
// K4 k_node_out (unchanged)
// ---------------------------------------------------------------------------
__global__ __launch_bounds__(256) void k_node_out(
    const unsigned short* __restrict__ aggrb, const unsigned short* __restrict__ pk,
    const float* __restrict__ x,
    const float* __restrict__ bg1, const float* __restrict__ bg2,
    float* __restrict__ out)
{
    __shared__ unsigned short gl[64 * 136];
    __shared__ float          ol[64 * 132];
    const int t  = threadIdx.x;
    const int w  = t >> 6, l = t & 63;
    const int lm = l & 15, q = l >> 4;
    const int rowb = blockIdx.x * 64;
    const int row0 = rowb + w * 16;

    const unsigned short* pkg1 = pk + 32768;
    const unsigned short* pkg2 = pk + 49152;

    floatx4 gacc[8];
    #pragma unroll
    for (int ct = 0; ct < 8; ++ct) gacc[ct] = 0.f;

    #pragma unroll
    for (int kc = 0; kc < 4; ++kc) {
        const short8 a = *(const short8*)(aggrb + (size_t)(row0 + lm) * DD + kc * 32 + q * 8);
        #pragma unroll
        for (int ct = 0; ct < 8; ++ct) {
            const short8 b = *(const short8*)(pkg1 + (size_t)((ct * 4 + kc) * 64 + l) * 8);
            gacc[ct] = __builtin_amdgcn_mfma_f32_16x16x32_bf16(a, b, gacc[ct], 0, 0, 0);
        }
    }

    #pragma unroll
    for (int ct = 0; ct < 8; ++ct) {
        const int col = ct * 16 + lm;
        const float b1 = bg1[col];
        #pragma unroll
        for (int r = 0; r < 4; ++r)
            gl[(w * 16 + q * 4 + r) * 136 + col] = f2bf(leaky1(gacc[ct][r] + b1));
    }
    __syncthreads();

    floatx4 oacc[8];
    #pragma unroll
    for (int ct = 0; ct < 8; ++ct) oacc[ct] = 0.f;

    #pragma unroll
    for (int kc = 0; kc < 4; ++kc) {
        const short8 a = *(const short8*)(gl + (size_t)(w * 16 + lm) * 136 + kc * 32 + q * 8);
        #pragma unroll
        for (int ct = 0; ct < 8; ++ct) {
            const short8 b = *(const short8*)(pkg2 + (size_t)((ct * 4 + kc) * 64 + l) * 8);
            oacc[ct] = __builtin_amdgcn_mfma_f32_16x16x32_bf16(a, b, oacc[ct], 0, 0, 0);
        }
    }

    __syncthreads();
    #pragma unroll
    for (int ct = 0; ct < 8; ++ct) {
        const int col = ct * 16 + lm;
        #pragma unroll
        for (int r = 0; r < 4; ++r)
            ol[(w * 16 + q * 4 + r) * 132 + col] = oacc[ct][r];
    }
    __syncthreads();

    #pragma unroll
    for (int k = 0; k < 8; ++k) {
        const int idx = t + k * 256;
        const int row = idx >> 5;
        const int c4  = (idx & 31) * 4;
        const float4 ov = *(const float4*)(ol + row * 132 + c4);
        const float4 bv = *(const float4*)(bg2 + c4);
        const size_t o  = (size_t)(rowb + row) * DD + c4;
        const float4 xv = *(const float4*)(x + o);
        float4 rv;
        rv.x = xv.x + ov.x + bv.x;
        rv.y = xv.y + ov.y + bv.y;
        rv.z = xv.z + ov.z + bv.z;
        rv.w = xv.w + ov.w + bv.w;
        *(float4*)(out + o) = rv;
    }
}

// ---------------------------------------------------------------------------
extern "C" void kernel_launch(void* const* d_in, const int* in_sizes, int n_in,
                              void* d_out, int out_size, void* d_ws, size_t ws_size,
                              hipStream_t stream)
{
    const float* x   = (const float*)d_in[0];
    const float* pos = (const float*)d_in[1];
    const int*   ei  = (const int*)d_in[2];
    const float* Wh1 = (const float*)d_in[3];
    const float* bh1 = (const float*)d_in[4];
    const float* Wh2 = (const float*)d_in[5];
    const float* bh2 = (const float*)d_in[6];
    const float* Wf1 = (const float*)d_in[7];
    const float* bf1 = (const float*)d_in[8];
    const float* Wg1 = (const float*)d_in[9];
    const float* bg1 = (const float*)d_in[10];
    const float* Wg2 = (const float*)d_in[11];
    const float* bg2 = (const float*)d_in[12];
    float* out = (float*)d_out;

    unsigned short* ub    = (unsigned short*)d_ws;          // NN*DD bf16
    unsigned short* aggrb = ub + (size_t)NN * DD;           // NN*DD bf16
    unsigned short* pk    = aggrb + (size_t)NN * DD;        // 4*16384 bf16
    float* delta = (float*)(pk + 65536);                    // NN*3
    int*   cnt   = (int*)(delta + (size_t)NN * 3);          // NN
    unsigned short* esrc = (unsigned short*)(cnt + NN);     // NN*CAP ushort

    k_init<<<160, 256, 0, stream>>>(Wh1, Wf1, Wg1, Wg2, cnt, pk);
    k_pre_scatter<<<2673, 512, 0, stream>>>(x, pk, pos, Wf1, bh1, Wh2, bh2, bf1,
                                            ei, ub, delta, cnt, esrc);
    k_gather<<<NN / 4, 256, 0, stream>>>(cnt, esrc, pos, delta, Wf1, ub, aggrb);
    k_node_out<<<NN / 64, 256, 0, stream>>>(aggrb, pk, x, bg1, bg2, out);
}